// Round 11
// baseline (2708.192 us; speedup 1.0000x reference)
//
#include <hip/hip_runtime.h>

#define T_LEN   512
#define H_DIM   128
#define OUT_DIM 7
#define BB      2
#define NBLK    256               // 1 block/CU
#define NTHREADS 768              // 12 waves = 3 layers x 4 waves
#define SKEW    9                 // layer skew; prologue phases 0,1,2 (mod 8)
#define P_TOT   (T_LEN + 2 * SKEW)   // 530 pipeline steps

// ws (bf16 units) layout:
#define WS_WIH  0                 // [(wv)*8+i'][kc][lane]*8 : (((wv*8+i)*4+kc)*512 + l*8)
#define WS_WHH3 196608            // [(wv)*8+i'][lane]*8     : ((wv*8+i)*512 + l*8)
#define WS_BIAS 245760            // f32 region: [wv*128 + i'*16 + q*4 + r]

typedef __bf16 bf16x8 __attribute__((ext_vector_type(8)));
typedef float  f32x4  __attribute__((ext_vector_type(4)));

struct __align__(16) SharedMem {
  float  xg[3][8][2][576];     // 110592 B  [ll][s][b][jpad]; jpad = 4j + 4*(j>>3)
  float  gx[12][2][160];       //  15360 B  [wv][b][slotpad]; off = 20i' + 4q
  float  z[2][H_DIM];          //   1024 B
  __bf16 ring[3][16][2][160];  //  30720 B  h rings [ll][t&15][b][k]
};                              // 157696 B

__device__ __forceinline__ float sigf(float x) {
  return __builtin_amdgcn_rcpf(1.f + __expf(-x));
}
__device__ __forceinline__ float tanh_fast(float x) {
  x = fminf(fmaxf(x, -15.f), 15.f);
  float e = __expf(2.f * x);
  return (e - 1.f) * __builtin_amdgcn_rcpf(e + 1.f);
}
__device__ __forceinline__ bf16x8 load8_f32_bf16(const float* p) {
  const f32x4 a = *(const f32x4*)p;
  const f32x4 b = *(const f32x4*)(p + 4);
  bf16x8 r;
  #pragma unroll
  for (int j = 0; j < 4; ++j) { r[j] = (__bf16)a[j]; r[4 + j] = (__bf16)b[j]; }
  return r;
}
__device__ __forceinline__ bf16x8 zero_bf16x8() {
  bf16x8 r;
  #pragma unroll
  for (int j = 0; j < 8; ++j) r[j] = (__bf16)0.f;
  return r;
}

// Wave-specialized layer pipeline: wave wv serves layer myll = wv>>2 (wl = wv&3),
// owning 8 M-tiles (mt = wl + 4i'). Permutation: MFMA row P = 16*mt+u <-> orig W
// row 128*(u&3) + (u>>2) + 4*wl + 16*i'  =>  acc[i'][r] = gate r (i,f,g,o) of
// j = q + 4*wl + 16*i', col n16 = batch. W_hh kc0-2 resident (96 VGPR), kc3
// streamed from ws; 530 serial slots; inter-layer via LDS h-rings.
__global__ __launch_bounds__(NTHREADS, 3)   // cap 170 VGPR -> 12 waves/CU
void lstm_kernel(const float* __restrict__ x,
                 const float* __restrict__ wih0, const float* __restrict__ whh0,
                 const float* __restrict__ bih0, const float* __restrict__ bhh0,
                 const float* __restrict__ wih1, const float* __restrict__ whh1,
                 const float* __restrict__ bih1, const float* __restrict__ bhh1,
                 const float* __restrict__ wih2, const float* __restrict__ whh2,
                 const float* __restrict__ bih2, const float* __restrict__ bhh2,
                 const float* __restrict__ fc1w, const float* __restrict__ fc1b,
                 const float* __restrict__ fc2w, const float* __restrict__ fc2b,
                 float* __restrict__ out, __bf16* __restrict__ ws)
{
  __shared__ SharedMem sh;
  const int tid  = threadIdx.x;
  const int wv   = tid >> 6;        // 0..11
  const int l    = tid & 63;
  const int q    = l >> 4;
  const int n16  = l & 15;          // MFMA col = batch slot (0,1 real)
  const int myll = wv >> 2;         // this wave's layer
  const int wl   = wv & 3;          // wave-within-layer
  const int bg   = blockIdx.x * BB;

  const float* WIH[3] = {wih0, wih1, wih2};
  const float* WHH[3] = {whh0, whh1, whh2};
  const float* BIH[3] = {bih0, bih1, bih2};
  const float* BHH[3] = {bhh0, bhh1, bhh2};

  const int rbase = ((n16 & 3) << 7) + (n16 >> 2) + (wl << 2);  // orig row, i'=0

  // ---- pre-pass: bf16 W_ih frags, W_hh kc3 frags, bias into ws ----
  #pragma unroll
  for (int i = 0; i < 8; ++i) {
    const int ro = rbase + (i << 4);
    #pragma unroll
    for (int kc = 0; kc < 4; ++kc) {
      bf16x8 v;
      if (myll == 0) {
        v = zero_bf16x8();
        if (q == 0 && kc == 0) v = load8_f32_bf16(wih0 + ro * 8);
      } else {
        v = load8_f32_bf16(WIH[myll] + ro * H_DIM + kc * 32 + q * 8);
      }
      *(bf16x8*)(ws + WS_WIH + ((size_t)(wv * 8 + i) * 4 + kc) * 512 + l * 8) = v;
    }
    *(bf16x8*)(ws + WS_WHH3 + (size_t)(wv * 8 + i) * 512 + l * 8) =
        load8_f32_bf16(WHH[myll] + ro * H_DIM + 96 + q * 8);
  }
  if (l < 32) {
    const int ii = l >> 2, qq = l & 3;
    const int j = qq + (wl << 2) + (ii << 4);
    f32x4 bv;
    #pragma unroll
    for (int r = 0; r < 4; ++r)
      bv[r] = BIH[myll][(r << 7) + j] + BHH[myll][(r << 7) + j];
    *(f32x4*)((float*)(ws + WS_BIAS) + wv * 128 + ii * 16 + qq * 4) = bv;
  }

  // ---- resident W_hh kc0..2 (96 VGPRs) ----
  bf16x8 whhf[8][3];
  #pragma unroll
  for (int i = 0; i < 8; ++i)
    #pragma unroll
    for (int kc = 0; kc < 3; ++kc)
      whhf[i][kc] = load8_f32_bf16(WHH[myll] + (rbase + (i << 4)) * H_DIM + kc * 32 + q * 8);

  // ---- ring slot 15 (t=-1) zero ----
  if (tid < 960) {
    const int ll2 = tid / 320, rem = tid % 320;
    sh.ring[ll2][15][rem / 160][rem % 160] = (__bf16)0.f;
  }

  // gate-lane constants: lane l -> (b = l>>5, slot = l&31) of this wave's layer
  const int gb   = l >> 5;
  const int slot = l & 31;
  const int gj   = (slot & 3) + (wl << 2) + ((slot >> 2) << 4);
  const int gxo  = slot * 4 + (slot >> 2) * 4;          // gx read offset
  const int xgrd = gj * 4 + ((gj >> 3) << 2);           // xg read offset
  const int aa   = q + (wl << 2);
  const int xgw0 = aa * 4 + ((aa >> 3) << 2);           // xg write base (+72*i')
  float c_st = 0.f;

  __syncthreads();   // pre-pass + LDS init visible (barrier drains vmcnt)

  const f32x4 ZV = {0.f, 0.f, 0.f, 0.f};
  const float* biasw = (const float*)(ws + WS_BIAS) + wv * 128;

  // ================= pipeline: 530 serial slots =================
  #pragma unroll 1
  for (int p = 0; p < P_TOT; ++p) {
    const int t   = p - SKEW * myll;        // wave-uniform
    const bool act = (t >= 0) && (t < T_LEN);

    if (act) {
      // ---- chunk prologue (every 8th layer-step): xg for 8 steps ----
      if ((t & 7) == 0) {
        const int trel = n16 >> 1, b = n16 & 1;   // col n16 = (trel, b)
        bf16x8 pb[4];
        if (myll == 0) {
          pb[0] = zero_bf16x8();
          if (q == 0)
            pb[0] = load8_f32_bf16(x + ((size_t)(bg + b) * T_LEN + t + trel) * 8);
        } else {
          #pragma unroll
          for (int kc = 0; kc < 4; ++kc)
            pb[kc] = *(const bf16x8*)&sh.ring[myll - 1][(t + trel) & 15][b][kc * 32 + q * 8];
        }
        #pragma unroll
        for (int i = 0; i < 8; ++i) {
          f32x4 acc = *(const f32x4*)(biasw + i * 16 + q * 4);
          if (myll == 0) {
            const bf16x8 wf = *(const bf16x8*)(ws + WS_WIH + (size_t)(wv * 8 + i) * 4 * 512 + l * 8);
            acc = __builtin_amdgcn_mfma_f32_16x16x32_bf16(wf, pb[0], acc, 0, 0, 0);
          } else {
            #pragma unroll
            for (int kc = 0; kc < 4; ++kc) {
              const bf16x8 wf = *(const bf16x8*)
                  (ws + WS_WIH + ((size_t)(wv * 8 + i) * 4 + kc) * 512 + l * 8);
              acc = __builtin_amdgcn_mfma_f32_16x16x32_bf16(wf, pb[kc], acc, 0, 0, 0);
            }
          }
          *(f32x4*)(&sh.xg[myll][trel][b][0] + xgw0 + 72 * i) = acc;
        }
      }

      // ---- recurrence step: W_hh x h(t-1); kc3 streamed from ws ----
      {
        bf16x8 hb[4];
        #pragma unroll
        for (int kc = 0; kc < 4; ++kc)
          hb[kc] = *(const bf16x8*)&sh.ring[myll][(t - 1) & 15][n16 & 1][kc * 32 + q * 8];
        #pragma unroll
        for (int i = 0; i < 8; i += 2) {
          const bf16x8 w3a = *(const bf16x8*)(ws + WS_WHH3 + (size_t)(wv * 8 + i) * 512 + l * 8);
          const bf16x8 w3b = *(const bf16x8*)(ws + WS_WHH3 + (size_t)(wv * 8 + i + 1) * 512 + l * 8);
          f32x4 a0 = ZV, a1 = ZV;
          #pragma unroll
          for (int kc = 0; kc < 3; ++kc) {
            a0 = __builtin_amdgcn_mfma_f32_16x16x32_bf16(whhf[i][kc],     hb[kc], a0, 0, 0, 0);
            a1 = __builtin_amdgcn_mfma_f32_16x16x32_bf16(whhf[i + 1][kc], hb[kc], a1, 0, 0, 0);
          }
          a0 = __builtin_amdgcn_mfma_f32_16x16x32_bf16(w3a, hb[3], a0, 0, 0, 0);
          a1 = __builtin_amdgcn_mfma_f32_16x16x32_bf16(w3b, hb[3], a1, 0, 0, 0);
          if (n16 < 2) {                    // b128 handoff, no transpose
            *(f32x4*)(&sh.gx[wv][n16][0] + 20 * i + 4 * q)       = a0;
            *(f32x4*)(&sh.gx[wv][n16][0] + 20 * (i + 1) + 4 * q) = a1;
          }
        }
      }
    }
    __builtin_amdgcn_wave_barrier();        // wave-private gx/xg; DS in-order

    if (act) {                              // gate phase: 64 dense lanes/wave
      const int s = t & 7;
      const f32x4 gv = *(const f32x4*)(&sh.gx[wv][gb][0] + gxo);
      const f32x4 xv = *(const f32x4*)(&sh.xg[myll][s][gb][0] + xgrd);
      const float gi = gv[0] + xv[0], gf = gv[1] + xv[1];
      const float gg = gv[2] + xv[2], go = gv[3] + xv[3];
      c_st = sigf(gf) * c_st + sigf(gi) * tanh_fast(gg);
      sh.ring[myll][t & 15][gb][gj] = (__bf16)(sigf(go) * tanh_fast(c_st));
    }
    __syncthreads();                        // h(t) visible block-wide for t+1
  }

  // ---- FC head: final h of layer 2 at t=511 -> ring slot 15 ----
  if (tid < 2 * H_DIM) {
    const int bb = tid >> 7, i = tid & 127;
    float a = fc1b[i];
    #pragma unroll 8
    for (int k = 0; k < H_DIM; ++k)
      a += (float)sh.ring[2][15][bb][k] * fc1w[i * H_DIM + k];
    sh.z[bb][i] = fmaxf(a, 0.f);
  }
  __syncthreads();
  if (tid < BB * OUT_DIM) {
    const int bb = tid / OUT_DIM, o = tid % OUT_DIM;
    float a = fc2b[o];
    for (int k = 0; k < H_DIM; ++k)
      a += sh.z[bb][k] * fc2w[o * H_DIM + k];
    out[(size_t)(bg + bb) * OUT_DIM + o] = a;
  }
}

extern "C" void kernel_launch(void* const* d_in, const int* in_sizes, int n_in,
                              void* d_out, int out_size, void* d_ws, size_t ws_size,
                              hipStream_t stream) {
  const float* x    = (const float*)d_in[0];
  const float* wih0 = (const float*)d_in[1];
  const float* whh0 = (const float*)d_in[2];
  const float* bih0 = (const float*)d_in[3];
  const float* bhh0 = (const float*)d_in[4];
  const float* wih1 = (const float*)d_in[5];
  const float* whh1 = (const float*)d_in[6];
  const float* bih1 = (const float*)d_in[7];
  const float* bhh1 = (const float*)d_in[8];
  const float* wih2 = (const float*)d_in[9];
  const float* whh2 = (const float*)d_in[10];
  const float* bih2 = (const float*)d_in[11];
  const float* bhh2 = (const float*)d_in[12];
  const float* fc1w = (const float*)d_in[13];
  const float* fc1b = (const float*)d_in[14];
  const float* fc2w = (const float*)d_in[15];
  const float* fc2b = (const float*)d_in[16];
  float* out = (float*)d_out;
  __bf16* ws = (__bf16*)d_ws;   // ~500 KB: bf16 W_ih / W_hh-kc3 frags + f32 bias

  lstm_kernel<<<dim3(NBLK), dim3(NTHREADS), 0, stream>>>(
      x, wih0, whh0, bih0, bhh0, wih1, whh1, bih1, bhh1,
      wih2, whh2, bih2, bhh2, fc1w, fc1b, fc2w, fc2b, out, ws);
}